// Round 11
// baseline (160.904 us; speedup 1.0000x reference)
//
#include <hip/hip_runtime.h>

#define F_IN 128
#define H_DIM 64
#define NBUCK_MAX 1024   // buckets of 128 nodes; N <= 131072

typedef short s16x8 __attribute__((ext_vector_type(8)));
typedef float f32x4 __attribute__((ext_vector_type(4)));

union FragU {
    s16x8 s;
    uint4 q;
    unsigned short u[8];
};

__device__ __forceinline__ unsigned short f2bf(float f) {
    unsigned int b = __float_as_uint(f);
    b += 0x7fffu + ((b >> 16) & 1u);
    return (unsigned short)(b >> 16);
}
__device__ __forceinline__ float bf2f(unsigned short u) {
    return __uint_as_float((unsigned int)u << 16);
}
__device__ __forceinline__ float bflo(unsigned int v) { return __uint_as_float(v << 16); }
__device__ __forceinline__ float bfhi(unsigned int v) { return __uint_as_float(v & 0xffff0000u); }

// ---------------- fused W prepack: both weights -> B-fragments bf16 ----------------
__device__ __forceinline__ void prepack_one(const float* __restrict__ W,
                                            unsigned short* __restrict__ wf, int KS, int tid) {
    int lane = tid & 63;
    int grp = tid >> 6;
    int ks = grp % KS;
    int ct = grp / KS;
    int col = ct * 16 + (lane & 15);
    int kbase = ks * 32 + (lane >> 4) * 8;
    FragU f;
#pragma unroll
    for (int j = 0; j < 8; ++j) f.u[j] = f2bf(W[(kbase + j) * H_DIM + col]);
    reinterpret_cast<uint4*>(wf)[tid] = f.q;
}

__global__ __launch_bounds__(256) void prepack_k(const float* __restrict__ W1, const float* __restrict__ W2,
                                                 unsigned short* __restrict__ wf1, unsigned short* __restrict__ wf2) {
    int tid = blockIdx.x * 256 + threadIdx.x;
    if (tid < 4 * 4 * 64) prepack_one(W1, wf1, 4, tid);
    else if (tid < 4 * 4 * 64 + 4 * 2 * 64) prepack_one(W2, wf2, 2, tid - 4 * 4 * 64);
}

// ---------------- MFMA GEMM1: hb = bf16(x @ W1) [N x 128]@[128 x 64] ----------------
__global__ __launch_bounds__(256) void gemm1_k(const float* __restrict__ x,
                                               const unsigned short* __restrict__ wf,
                                               unsigned short* __restrict__ outb, int N) {
    constexpr int KS = F_IN / 32;
    int wv = threadIdx.x >> 6;
    int lane = threadIdx.x & 63;
    int rb = blockIdx.x * 64 + wv * 16;
    int ra = rb + (lane & 15);
    if (ra > N - 1) ra = N - 1;
    int koct = lane >> 4;

    FragU af[KS];
    const float* ap = x + (size_t)ra * F_IN + koct * 8;
#pragma unroll
    for (int ks = 0; ks < KS; ++ks) {
        float4 v0 = *reinterpret_cast<const float4*>(ap + ks * 32);
        float4 v1 = *reinterpret_cast<const float4*>(ap + ks * 32 + 4);
        af[ks].u[0] = f2bf(v0.x); af[ks].u[1] = f2bf(v0.y);
        af[ks].u[2] = f2bf(v0.z); af[ks].u[3] = f2bf(v0.w);
        af[ks].u[4] = f2bf(v1.x); af[ks].u[5] = f2bf(v1.y);
        af[ks].u[6] = f2bf(v1.z); af[ks].u[7] = f2bf(v1.w);
    }

    const uint4* bq = reinterpret_cast<const uint4*>(wf);
    f32x4 acc[4];
#pragma unroll
    for (int ct = 0; ct < 4; ++ct) acc[ct] = (f32x4){0.f, 0.f, 0.f, 0.f};
#pragma unroll
    for (int ct = 0; ct < 4; ++ct) {
#pragma unroll
        for (int ks = 0; ks < KS; ++ks) {
            FragU b;
            b.q = bq[(ct * KS + ks) * 64 + lane];
            acc[ct] = __builtin_amdgcn_mfma_f32_16x16x32_bf16(af[ks].s, b.s, acc[ct], 0, 0, 0);
        }
    }

    int ro_base = rb + (lane >> 4) * 4;
    int col = lane & 15;
#pragma unroll
    for (int ct = 0; ct < 4; ++ct) {
#pragma unroll
        for (int j = 0; j < 4; ++j) {
            int ro = ro_base + j;
            if (ro < N) outb[(size_t)ro * H_DIM + ct * 16 + col] = f2bf(acc[ct][j]);
        }
    }
}

// ---------------- MFMA GEMM2 + fused proj: uz[row] = (z2row·A0, z2row·A1, z2row·B0, z2row·B1)
__global__ __launch_bounds__(256) void gemm2v_k(const unsigned short* __restrict__ a1b,
                                                const unsigned short* __restrict__ wf,
                                                const float* __restrict__ Wlin,  // [2,128]
                                                float4* __restrict__ uz, int N) {
    constexpr int KS = H_DIM / 32;
    int wv = threadIdx.x >> 6;
    int lane = threadIdx.x & 63;
    int rb = blockIdx.x * 64 + wv * 16;
    int ra = rb + (lane & 15);
    if (ra > N - 1) ra = N - 1;
    int koct = lane >> 4;

    FragU af[KS];
    const unsigned short* ap = a1b + (size_t)ra * H_DIM + koct * 8;
#pragma unroll
    for (int ks = 0; ks < KS; ++ks)
        af[ks].q = *reinterpret_cast<const uint4*>(ap + ks * 32);

    const uint4* bq = reinterpret_cast<const uint4*>(wf);
    f32x4 acc[4];
#pragma unroll
    for (int ct = 0; ct < 4; ++ct) acc[ct] = (f32x4){0.f, 0.f, 0.f, 0.f};
#pragma unroll
    for (int ct = 0; ct < 4; ++ct) {
#pragma unroll
        for (int ks = 0; ks < KS; ++ks) {
            FragU b;
            b.q = bq[(ct * KS + ks) * 64 + lane];
            acc[ct] = __builtin_amdgcn_mfma_f32_16x16x32_bf16(af[ks].s, b.s, acc[ct], 0, 0, 0);
        }
    }

    int c = lane & 15;
    float w0[4], w1[4], w2[4], w3[4];
#pragma unroll
    for (int ct = 0; ct < 4; ++ct) {
        int col = ct * 16 + c;
        w0[ct] = Wlin[col];        // A0
        w1[ct] = Wlin[128 + col];  // A1
        w2[ct] = Wlin[64 + col];   // B0
        w3[ct] = Wlin[192 + col];  // B1
    }
    int ro_base = rb + (lane >> 4) * 4;
#pragma unroll
    for (int j = 0; j < 4; ++j) {
        float p0 = 0.f, p1 = 0.f, p2 = 0.f, p3 = 0.f;
#pragma unroll
        for (int ct = 0; ct < 4; ++ct) {
            float zv = acc[ct][j];
            p0 = fmaf(zv, w0[ct], p0);
            p1 = fmaf(zv, w1[ct], p1);
            p2 = fmaf(zv, w2[ct], p2);
            p3 = fmaf(zv, w3[ct], p3);
        }
#pragma unroll
        for (int m = 1; m < 16; m <<= 1) {
            p0 += __shfl_xor(p0, m);
            p1 += __shfl_xor(p1, m);
            p2 += __shfl_xor(p2, m);
            p3 += __shfl_xor(p3, m);
        }
        int ro = ro_base + j;
        if (c == 0 && ro < N) uz[ro] = make_float4(p0, p1, p2, p3);
    }
}

// ---------------- binning sort: global bucket histogram ----------------
__global__ __launch_bounds__(256) void ghist_k(const int* __restrict__ ei,
                                               int* __restrict__ ghist, int E, int nbuck) {
    __shared__ int h[NBUCK_MAX];
    int tid = threadIdx.x;
    for (int i = tid; i < nbuck; i += 256) h[i] = 0;
    __syncthreads();
    int e0 = blockIdx.x * 8192;
    int ecount = min(8192, E - e0);
    for (int i = tid; i < ecount; i += 256)
        atomicAdd(&h[ei[E + e0 + i] >> 7], 1);
    __syncthreads();
    for (int i = tid; i < nbuck; i += 256)
        if (h[i]) atomicAdd(&ghist[i], h[i]);
}

// ---------------- bucket scan ----------------
__global__ __launch_bounds__(256) void gscan_k(const int* __restrict__ ghist,
                                               int* __restrict__ gstart, int* __restrict__ gcursor,
                                               int nbuck, int E) {
    __shared__ int wsum[256];
    int tid = threadIdx.x;
    int idx4 = tid * 4;
    int c[4];
    int mysum = 0;
#pragma unroll
    for (int j = 0; j < 4; ++j) {
        c[j] = (idx4 + j < nbuck) ? ghist[idx4 + j] : 0;
        mysum += c[j];
    }
    wsum[tid] = mysum;
    __syncthreads();
    for (int off = 1; off < 256; off <<= 1) {
        int add = (tid >= off) ? wsum[tid - off] : 0;
        __syncthreads();
        wsum[tid] += add;
        __syncthreads();
    }
    int run = wsum[tid] - mysum;
#pragma unroll
    for (int j = 0; j < 4; ++j) {
        if (idx4 + j < nbuck) { gstart[idx4 + j] = run; gcursor[idx4 + j] = run; }
        run += c[j];
    }
    if (tid == 255) gstart[nbuck] = E;
}

// ---------------- binA: LDS counting-sort chunk by bucket, grouped global write ----------------
__global__ __launch_bounds__(256) void binA_k(const int* __restrict__ ei, const float* __restrict__ ew,
                                              int* __restrict__ gcursor,
                                              unsigned long long* __restrict__ stage, int E, int nbuck) {
    __shared__ unsigned long long sstage[4096];
    __shared__ int smeta[4096];
    __shared__ int cnt[NBUCK_MAX];
    __shared__ int lbase[NBUCK_MAX];
    __shared__ int gbase[NBUCK_MAX];
    __shared__ int cur[NBUCK_MAX];
    __shared__ int wsum[256];
    int tid = threadIdx.x;
    int e0 = blockIdx.x * 4096;
    int ecount = min(4096, E - e0);
    for (int i = tid; i < nbuck; i += 256) { cnt[i] = 0; cur[i] = 0; }
    __syncthreads();
    for (int i = tid; i < ecount; i += 256)
        atomicAdd(&cnt[ei[E + e0 + i] >> 7], 1);
    __syncthreads();
    int idx4 = tid * 4;
    int c[4];
    int mysum = 0;
#pragma unroll
    for (int j = 0; j < 4; ++j) {
        c[j] = (idx4 + j < nbuck) ? cnt[idx4 + j] : 0;
        mysum += c[j];
    }
    wsum[tid] = mysum;
    __syncthreads();
    for (int off = 1; off < 256; off <<= 1) {
        int add = (tid >= off) ? wsum[tid - off] : 0;
        __syncthreads();
        wsum[tid] += add;
        __syncthreads();
    }
    int run = wsum[tid] - mysum;
#pragma unroll
    for (int j = 0; j < 4; ++j) {
        if (idx4 + j < nbuck) lbase[idx4 + j] = run;
        run += c[j];
    }
    __syncthreads();
    for (int b = tid; b < nbuck; b += 256)
        gbase[b] = cnt[b] ? atomicAdd(&gcursor[b], cnt[b]) : 0;
    __syncthreads();
    for (int i = tid; i < ecount; i += 256) {
        int e = e0 + i;
        int s = ei[e];
        int d = ei[E + e];
        unsigned int wb = __float_as_uint(ew[e]);
        int b = d >> 7;
        int off = atomicAdd(&cur[b], 1);
        int pos = lbase[b] + off;
        sstage[pos] = ((unsigned long long)(d & 127) << 49)
                    | ((unsigned long long)(unsigned int)s << 32) | wb;
        smeta[pos] = gbase[b] + off;
    }
    __syncthreads();
    for (int i = tid; i < ecount; i += 256)
        stage[smeta[i]] = sstage[i];
}

// ---------------- binB: per-bucket counting sort -> final CSR epack + rdeg(int2) ----------------
__global__ __launch_bounds__(256) void binB_k(const unsigned long long* __restrict__ stage,
                                              const int* __restrict__ gstart,
                                              unsigned long long* __restrict__ epack,
                                              int2* __restrict__ rdeg, int N) {
    __shared__ unsigned long long lout[2048];
    __shared__ int cnt[128], exc[128], cur[128];
    int b = blockIdx.x;
    int tid = threadIdx.x;
    int base = gstart[b];
    int nb = gstart[b + 1] - base;
    if (tid < 128) { cnt[tid] = 0; cur[tid] = 0; }
    __syncthreads();
    for (int i = tid; i < nb; i += 256)
        atomicAdd(&cnt[(int)((stage[base + i] >> 49) & 127)], 1);
    __syncthreads();
    if (tid < 128) exc[tid] = cnt[tid];
    __syncthreads();
    for (int off = 1; off < 128; off <<= 1) {
        int add = (tid >= off && tid < 128) ? exc[tid - off] : 0;
        __syncthreads();
        if (tid < 128) exc[tid] += add;
        __syncthreads();
    }
    int node0 = b * 128;
    if (tid < 128) {
        exc[tid] -= cnt[tid];  // exclusive
        int node = node0 + tid;
        if (node < N) rdeg[node] = make_int2(base + exc[tid], cnt[tid]);
    }
    __syncthreads();
    for (int i = tid; i < nb; i += 256) {
        unsigned long long v = stage[base + i];
        int dl = (int)((v >> 49) & 127);
        unsigned int src = (unsigned int)((v >> 32) & 0x1FFFF);
        unsigned int wb = (unsigned int)v;
        int pos = exc[dl] + atomicAdd(&cur[dl], 1);
        unsigned long long outv = ((unsigned long long)wb << 32) | src;
        if (pos < 2048) lout[pos] = outv;
        else epack[base + pos] = outv;
    }
    __syncthreads();
    int lim = min(nb, 2048);
    for (int i = tid; i < lim; i += 256)
        epack[base + i] = lout[i];
}

// ---------------- agg1 (16-way row-split): outb[n,:] = bf16(relu(sum_j w_j*hb[src_j,:])) ----------------
// Wave per node; lane = slot(0..15)*4 + dimg(0..3). Each lane gathers 2x uint4
// (32B, dims [dimg*16, +16)); 16 edges + 32 gather-loads in flight per wave.
// 97% of nodes (Poisson deg~10) complete in ONE gather round.
__global__ __launch_bounds__(256) void agg1_k(const unsigned short* __restrict__ hb,
                                              const int2* __restrict__ rdeg,
                                              const unsigned long long* __restrict__ epack,
                                              unsigned short* __restrict__ outb, int N) {
    int node = blockIdx.x * 4 + (threadIdx.x >> 6);
    if (node >= N) return;
    int lane = threadIdx.x & 63;
    int slot = lane >> 2;   // 0..15
    int dimg = lane & 3;    // 0..3, dims [dimg*16, dimg*16+16)
    int2 rd = rdeg[node];
    int start = rd.x, cnt = rd.y;
    float a[16];
#pragma unroll
    for (int q = 0; q < 16; ++q) a[q] = 0.f;
    for (int j = slot; j < cnt; j += 16) {
        unsigned long long p = epack[start + j];
        float w = __uint_as_float((unsigned int)(p >> 32));
        unsigned int src = (unsigned int)p;
        const uint4* rp = reinterpret_cast<const uint4*>(hb + (size_t)src * H_DIM + dimg * 16);
        uint4 v0 = rp[0];
        uint4 v1 = rp[1];
        a[0]  = fmaf(w, bflo(v0.x), a[0]);  a[1]  = fmaf(w, bfhi(v0.x), a[1]);
        a[2]  = fmaf(w, bflo(v0.y), a[2]);  a[3]  = fmaf(w, bfhi(v0.y), a[3]);
        a[4]  = fmaf(w, bflo(v0.z), a[4]);  a[5]  = fmaf(w, bfhi(v0.z), a[5]);
        a[6]  = fmaf(w, bflo(v0.w), a[6]);  a[7]  = fmaf(w, bfhi(v0.w), a[7]);
        a[8]  = fmaf(w, bflo(v1.x), a[8]);  a[9]  = fmaf(w, bfhi(v1.x), a[9]);
        a[10] = fmaf(w, bflo(v1.y), a[10]); a[11] = fmaf(w, bfhi(v1.y), a[11]);
        a[12] = fmaf(w, bflo(v1.z), a[12]); a[13] = fmaf(w, bfhi(v1.z), a[13]);
        a[14] = fmaf(w, bflo(v1.w), a[14]); a[15] = fmaf(w, bfhi(v1.w), a[15]);
    }
    // reduce across the 16 slots (lanes sharing dimg): xor 4, 8, 16, 32
#pragma unroll
    for (int q = 0; q < 16; ++q) {
        a[q] += __shfl_xor(a[q], 4);
        a[q] += __shfl_xor(a[q], 8);
        a[q] += __shfl_xor(a[q], 16);
        a[q] += __shfl_xor(a[q], 32);
    }
    if (slot == 0) {
        uint4 o0, o1;
        o0.x = (unsigned int)f2bf(fmaxf(a[0], 0.f))  | ((unsigned int)f2bf(fmaxf(a[1], 0.f)) << 16);
        o0.y = (unsigned int)f2bf(fmaxf(a[2], 0.f))  | ((unsigned int)f2bf(fmaxf(a[3], 0.f)) << 16);
        o0.z = (unsigned int)f2bf(fmaxf(a[4], 0.f))  | ((unsigned int)f2bf(fmaxf(a[5], 0.f)) << 16);
        o0.w = (unsigned int)f2bf(fmaxf(a[6], 0.f))  | ((unsigned int)f2bf(fmaxf(a[7], 0.f)) << 16);
        o1.x = (unsigned int)f2bf(fmaxf(a[8], 0.f))  | ((unsigned int)f2bf(fmaxf(a[9], 0.f)) << 16);
        o1.y = (unsigned int)f2bf(fmaxf(a[10], 0.f)) | ((unsigned int)f2bf(fmaxf(a[11], 0.f)) << 16);
        o1.z = (unsigned int)f2bf(fmaxf(a[12], 0.f)) | ((unsigned int)f2bf(fmaxf(a[13], 0.f)) << 16);
        o1.w = (unsigned int)f2bf(fmaxf(a[14], 0.f)) | ((unsigned int)f2bf(fmaxf(a[15], 0.f)) << 16);
        uint4* op = reinterpret_cast<uint4*>(outb + (size_t)node * H_DIM + dimg * 16);
        op[0] = o0;
        op[1] = o1;
    }
}

// ---------------- aggv: u[n] = sum_j w_j * uz[src_j]  (thread per node, float4) ----------------
__global__ __launch_bounds__(256) void aggv_k(const float4* __restrict__ uz,
                                              const int2* __restrict__ rdeg,
                                              const unsigned long long* __restrict__ epack,
                                              float4* __restrict__ u, int N) {
    int node = blockIdx.x * 256 + threadIdx.x;
    if (node >= N) return;
    int2 rd = rdeg[node];
    int start = rd.x, cnt = rd.y;
    float4 acc = make_float4(0.f, 0.f, 0.f, 0.f);
    int j = 0;
    for (; j + 3 < cnt; j += 4) {
#pragma unroll
        for (int q = 0; q < 4; ++q) {
            unsigned long long p = epack[start + j + q];
            float w = __uint_as_float((unsigned int)(p >> 32));
            float4 v = uz[(unsigned int)p];
            acc.x = fmaf(w, v.x, acc.x);
            acc.y = fmaf(w, v.y, acc.y);
            acc.z = fmaf(w, v.z, acc.z);
            acc.w = fmaf(w, v.w, acc.w);
        }
    }
    for (; j < cnt; ++j) {
        unsigned long long p = epack[start + j];
        float w = __uint_as_float((unsigned int)(p >> 32));
        float4 v = uz[(unsigned int)p];
        acc.x = fmaf(w, v.x, acc.x);
        acc.y = fmaf(w, v.y, acc.y);
        acc.z = fmaf(w, v.z, acc.z);
        acc.w = fmaf(w, v.w, acc.w);
    }
    u[node] = acc;
}

// ---------------- pair decode ----------------
__global__ __launch_bounds__(256) void pair_k(const float4* __restrict__ u,
                                              const int* __restrict__ pos,  // [2,P] flat
                                              float2* __restrict__ out, int P) {
    int p = blockIdx.x * 256 + threadIdx.x;
    if (p >= P) return;
    int s = pos[p];
    int t = pos[P + p];
    float4 us = u[s];
    float4 ut = u[t];
    union { float f[2]; unsigned long long v; } o;
    o.f[0] = us.x + ut.z;
    o.f[1] = us.y + ut.w;
    __builtin_nontemporal_store(o.v, reinterpret_cast<unsigned long long*>(&out[p]));
}

extern "C" void kernel_launch(void* const* d_in, const int* in_sizes, int n_in,
                              void* d_out, int out_size, void* d_ws, size_t ws_size,
                              hipStream_t stream) {
    const float* x    = (const float*)d_in[0];
    const int*   ei   = (const int*)d_in[1];    // [2,E]
    const float* ew   = (const float*)d_in[2];  // [E]
    const int*   pos  = (const int*)d_in[3];    // [2,P]
    const float* W1   = (const float*)d_in[4];  // [128,64]
    const float* W2   = (const float*)d_in[5];  // [64,64]
    const float* Wlin = (const float*)d_in[6];  // [2,128]
    float* out = (float*)d_out;

    const int N = in_sizes[0] / F_IN;      // 100000
    const int E = in_sizes[2];             // 1000000
    const int P = in_sizes[3] / 2;         // 500000
    const int nbuck = (N + 127) / 128;     // 782

    // workspace layout (bytes)
    char* ws = (char*)d_ws;
    const size_t rowBF = (size_t)N * H_DIM * sizeof(unsigned short);  // 12.8 MB
    unsigned short* hb   = (unsigned short*)ws;                // gemm1 out (bf16)
    unsigned short* a1b  = (unsigned short*)(ws + rowBF);      // relu(agg1) (bf16)
    float4*         uz   = (float4*)(ws + 2 * rowBF);          // N float4
    float4*         u    = uz + N;                             // N float4
    unsigned long long* epack = (unsigned long long*)((char*)(u + N));
    unsigned long long* stage = epack + E;
    int* ghist   = (int*)(stage + E);
    int* gstart  = ghist + NBUCK_MAX;          // nbuck+1
    int* gcursor = gstart + NBUCK_MAX + 1;
    int2* rdeg   = (int2*)(gcursor + NBUCK_MAX);
    size_t wf_off = (((size_t)((char*)(rdeg + N) - ws)) + 15) & ~(size_t)15;
    unsigned short* wf1 = (unsigned short*)(ws + wf_off);      // 16 KB
    unsigned short* wf2 = wf1 + 4 * 4 * 64 * 8;                // 8 KB

    // weight prepack (single launch: 4 blocks W1 + 2 blocks W2)
    prepack_k<<<6, 256, 0, stream>>>(W1, W2, wf1, wf2);

    // conv1 matmul (x f32 -> bf16 in-register) -> hb
    gemm1_k<<<(N + 63) / 64, 256, 0, stream>>>(x, wf1, hb, N);

    // binning sort -> CSR (epack, rdeg)
    hipMemsetAsync(ghist, 0, (size_t)nbuck * sizeof(int), stream);
    ghist_k<<<(E + 8191) / 8192, 256, 0, stream>>>(ei, ghist, E, nbuck);
    gscan_k<<<1, 256, 0, stream>>>(ghist, gstart, gcursor, nbuck, E);
    binA_k<<<(E + 4095) / 4096, 256, 0, stream>>>(ei, ew, gcursor, stage, E, nbuck);
    binB_k<<<nbuck, 256, 0, stream>>>(stage, gstart, epack, rdeg, N);

    // agg1: hb -> a1b (bf16, relu fused)
    agg1_k<<<(N + 3) / 4, 256, 0, stream>>>(hb, rdeg, epack, a1b, N);
    // conv2 matmul + fused projection: a1b -> uz
    gemm2v_k<<<(N + 63) / 64, 256, 0, stream>>>(a1b, wf2, Wlin, uz, N);
    // agg2 on projected vectors: uz -> u
    aggv_k<<<(N + 255) / 256, 256, 0, stream>>>(uz, rdeg, epack, u, N);
    // pair decode
    pair_k<<<(P + 255) / 256, 256, 0, stream>>>(u, pos, (float2*)out, P);
}

// Round 12
// 118.817 us; speedup vs baseline: 1.3542x; 1.3542x over previous
//
#include <hip/hip_runtime.h>

#define F_IN 128
#define H_DIM 64
#define NBUCK_MAX 1024   // buckets of 128 nodes; N <= 131072

typedef short s16x8 __attribute__((ext_vector_type(8)));
typedef float f32x4 __attribute__((ext_vector_type(4)));
typedef float f32x2 __attribute__((ext_vector_type(2)));

union FragU {
    s16x8 s;
    uint4 q;
    unsigned short u[8];
};

__device__ __forceinline__ unsigned short f2bf(float f) {
    unsigned int b = __float_as_uint(f);
    b += 0x7fffu + ((b >> 16) & 1u);
    return (unsigned short)(b >> 16);
}
__device__ __forceinline__ float bf2f(unsigned short u) {
    return __uint_as_float((unsigned int)u << 16);
}
// unpack u32 (2 bf16) -> f32x2
__device__ __forceinline__ f32x2 up2(unsigned int v) {
    f32x2 r;
    r.x = __uint_as_float(v << 16);
    r.y = __uint_as_float(v & 0xffff0000u);
    return r;
}
__device__ __forceinline__ f32x2 fma2(f32x2 a, f32x2 b, f32x2 c) {
#if __has_builtin(__builtin_elementwise_fma)
    return __builtin_elementwise_fma(a, b, c);
#else
    f32x2 r;
    r.x = fmaf(a.x, b.x, c.x);
    r.y = fmaf(a.y, b.y, c.y);
    return r;
#endif
}

// ---------------- fused W prepack: both weights -> B-fragments bf16 ----------------
__device__ __forceinline__ void prepack_one(const float* __restrict__ W,
                                            unsigned short* __restrict__ wf, int KS, int tid) {
    int lane = tid & 63;
    int grp = tid >> 6;
    int ks = grp % KS;
    int ct = grp / KS;
    int col = ct * 16 + (lane & 15);
    int kbase = ks * 32 + (lane >> 4) * 8;
    FragU f;
#pragma unroll
    for (int j = 0; j < 8; ++j) f.u[j] = f2bf(W[(kbase + j) * H_DIM + col]);
    reinterpret_cast<uint4*>(wf)[tid] = f.q;
}

__global__ __launch_bounds__(256) void prepack_k(const float* __restrict__ W1, const float* __restrict__ W2,
                                                 unsigned short* __restrict__ wf1, unsigned short* __restrict__ wf2) {
    int tid = blockIdx.x * 256 + threadIdx.x;
    if (tid < 4 * 4 * 64) prepack_one(W1, wf1, 4, tid);
    else if (tid < 4 * 4 * 64 + 4 * 2 * 64) prepack_one(W2, wf2, 2, tid - 4 * 4 * 64);
}

// ---------------- MFMA GEMM1: hb = bf16(x @ W1) [N x 128]@[128 x 64] ----------------
__global__ __launch_bounds__(256) void gemm1_k(const float* __restrict__ x,
                                               const unsigned short* __restrict__ wf,
                                               unsigned short* __restrict__ outb, int N) {
    constexpr int KS = F_IN / 32;
    int wv = threadIdx.x >> 6;
    int lane = threadIdx.x & 63;
    int rb = blockIdx.x * 64 + wv * 16;
    int ra = rb + (lane & 15);
    if (ra > N - 1) ra = N - 1;
    int koct = lane >> 4;

    FragU af[KS];
    const float* ap = x + (size_t)ra * F_IN + koct * 8;
#pragma unroll
    for (int ks = 0; ks < KS; ++ks) {
        float4 v0 = *reinterpret_cast<const float4*>(ap + ks * 32);
        float4 v1 = *reinterpret_cast<const float4*>(ap + ks * 32 + 4);
        af[ks].u[0] = f2bf(v0.x); af[ks].u[1] = f2bf(v0.y);
        af[ks].u[2] = f2bf(v0.z); af[ks].u[3] = f2bf(v0.w);
        af[ks].u[4] = f2bf(v1.x); af[ks].u[5] = f2bf(v1.y);
        af[ks].u[6] = f2bf(v1.z); af[ks].u[7] = f2bf(v1.w);
    }

    const uint4* bq = reinterpret_cast<const uint4*>(wf);
    f32x4 acc[4];
#pragma unroll
    for (int ct = 0; ct < 4; ++ct) acc[ct] = (f32x4){0.f, 0.f, 0.f, 0.f};
#pragma unroll
    for (int ct = 0; ct < 4; ++ct) {
#pragma unroll
        for (int ks = 0; ks < KS; ++ks) {
            FragU b;
            b.q = bq[(ct * KS + ks) * 64 + lane];
            acc[ct] = __builtin_amdgcn_mfma_f32_16x16x32_bf16(af[ks].s, b.s, acc[ct], 0, 0, 0);
        }
    }

    int ro_base = rb + (lane >> 4) * 4;
    int col = lane & 15;
#pragma unroll
    for (int ct = 0; ct < 4; ++ct) {
#pragma unroll
        for (int j = 0; j < 4; ++j) {
            int ro = ro_base + j;
            if (ro < N) outb[(size_t)ro * H_DIM + ct * 16 + col] = f2bf(acc[ct][j]);
        }
    }
}

// ---------------- MFMA GEMM2 + fused proj: uz[row] = (z2row·A0, z2row·A1, z2row·B0, z2row·B1)
__global__ __launch_bounds__(256) void gemm2v_k(const unsigned short* __restrict__ a1b,
                                                const unsigned short* __restrict__ wf,
                                                const float* __restrict__ Wlin,  // [2,128]
                                                float4* __restrict__ uz, int N) {
    constexpr int KS = H_DIM / 32;
    int wv = threadIdx.x >> 6;
    int lane = threadIdx.x & 63;
    int rb = blockIdx.x * 64 + wv * 16;
    int ra = rb + (lane & 15);
    if (ra > N - 1) ra = N - 1;
    int koct = lane >> 4;

    FragU af[KS];
    const unsigned short* ap = a1b + (size_t)ra * H_DIM + koct * 8;
#pragma unroll
    for (int ks = 0; ks < KS; ++ks)
        af[ks].q = *reinterpret_cast<const uint4*>(ap + ks * 32);

    const uint4* bq = reinterpret_cast<const uint4*>(wf);
    f32x4 acc[4];
#pragma unroll
    for (int ct = 0; ct < 4; ++ct) acc[ct] = (f32x4){0.f, 0.f, 0.f, 0.f};
#pragma unroll
    for (int ct = 0; ct < 4; ++ct) {
#pragma unroll
        for (int ks = 0; ks < KS; ++ks) {
            FragU b;
            b.q = bq[(ct * KS + ks) * 64 + lane];
            acc[ct] = __builtin_amdgcn_mfma_f32_16x16x32_bf16(af[ks].s, b.s, acc[ct], 0, 0, 0);
        }
    }

    int c = lane & 15;
    float w0[4], w1[4], w2[4], w3[4];
#pragma unroll
    for (int ct = 0; ct < 4; ++ct) {
        int col = ct * 16 + c;
        w0[ct] = Wlin[col];        // A0
        w1[ct] = Wlin[128 + col];  // A1
        w2[ct] = Wlin[64 + col];   // B0
        w3[ct] = Wlin[192 + col];  // B1
    }
    int ro_base = rb + (lane >> 4) * 4;
#pragma unroll
    for (int j = 0; j < 4; ++j) {
        float p0 = 0.f, p1 = 0.f, p2 = 0.f, p3 = 0.f;
#pragma unroll
        for (int ct = 0; ct < 4; ++ct) {
            float zv = acc[ct][j];
            p0 = fmaf(zv, w0[ct], p0);
            p1 = fmaf(zv, w1[ct], p1);
            p2 = fmaf(zv, w2[ct], p2);
            p3 = fmaf(zv, w3[ct], p3);
        }
#pragma unroll
        for (int m = 1; m < 16; m <<= 1) {
            p0 += __shfl_xor(p0, m);
            p1 += __shfl_xor(p1, m);
            p2 += __shfl_xor(p2, m);
            p3 += __shfl_xor(p3, m);
        }
        int ro = ro_base + j;
        if (c == 0 && ro < N) uz[ro] = make_float4(p0, p1, p2, p3);
    }
}

// ---------------- binning sort: global bucket histogram ----------------
__global__ __launch_bounds__(256) void ghist_k(const int* __restrict__ ei,
                                               int* __restrict__ ghist, int E, int nbuck) {
    __shared__ int h[NBUCK_MAX];
    int tid = threadIdx.x;
    for (int i = tid; i < nbuck; i += 256) h[i] = 0;
    __syncthreads();
    int e0 = blockIdx.x * 8192;
    int ecount = min(8192, E - e0);
    for (int i = tid; i < ecount; i += 256)
        atomicAdd(&h[ei[E + e0 + i] >> 7], 1);
    __syncthreads();
    for (int i = tid; i < nbuck; i += 256)
        if (h[i]) atomicAdd(&ghist[i], h[i]);
}

// ---------------- bucket scan ----------------
__global__ __launch_bounds__(256) void gscan_k(const int* __restrict__ ghist,
                                               int* __restrict__ gstart, int* __restrict__ gcursor,
                                               int nbuck, int E) {
    __shared__ int wsum[256];
    int tid = threadIdx.x;
    int idx4 = tid * 4;
    int c[4];
    int mysum = 0;
#pragma unroll
    for (int j = 0; j < 4; ++j) {
        c[j] = (idx4 + j < nbuck) ? ghist[idx4 + j] : 0;
        mysum += c[j];
    }
    wsum[tid] = mysum;
    __syncthreads();
    for (int off = 1; off < 256; off <<= 1) {
        int add = (tid >= off) ? wsum[tid - off] : 0;
        __syncthreads();
        wsum[tid] += add;
        __syncthreads();
    }
    int run = wsum[tid] - mysum;
#pragma unroll
    for (int j = 0; j < 4; ++j) {
        if (idx4 + j < nbuck) { gstart[idx4 + j] = run; gcursor[idx4 + j] = run; }
        run += c[j];
    }
    if (tid == 255) gstart[nbuck] = E;
}

// ---------------- binA: LDS counting-sort chunk by bucket, grouped global write ----------------
__global__ __launch_bounds__(256) void binA_k(const int* __restrict__ ei, const float* __restrict__ ew,
                                              int* __restrict__ gcursor,
                                              unsigned long long* __restrict__ stage, int E, int nbuck) {
    __shared__ unsigned long long sstage[4096];
    __shared__ int smeta[4096];
    __shared__ int cnt[NBUCK_MAX];
    __shared__ int lbase[NBUCK_MAX];
    __shared__ int gbase[NBUCK_MAX];
    __shared__ int cur[NBUCK_MAX];
    __shared__ int wsum[256];
    int tid = threadIdx.x;
    int e0 = blockIdx.x * 4096;
    int ecount = min(4096, E - e0);
    for (int i = tid; i < nbuck; i += 256) { cnt[i] = 0; cur[i] = 0; }
    __syncthreads();
    for (int i = tid; i < ecount; i += 256)
        atomicAdd(&cnt[ei[E + e0 + i] >> 7], 1);
    __syncthreads();
    int idx4 = tid * 4;
    int c[4];
    int mysum = 0;
#pragma unroll
    for (int j = 0; j < 4; ++j) {
        c[j] = (idx4 + j < nbuck) ? cnt[idx4 + j] : 0;
        mysum += c[j];
    }
    wsum[tid] = mysum;
    __syncthreads();
    for (int off = 1; off < 256; off <<= 1) {
        int add = (tid >= off) ? wsum[tid - off] : 0;
        __syncthreads();
        wsum[tid] += add;
        __syncthreads();
    }
    int run = wsum[tid] - mysum;
#pragma unroll
    for (int j = 0; j < 4; ++j) {
        if (idx4 + j < nbuck) lbase[idx4 + j] = run;
        run += c[j];
    }
    __syncthreads();
    for (int b = tid; b < nbuck; b += 256)
        gbase[b] = cnt[b] ? atomicAdd(&gcursor[b], cnt[b]) : 0;
    __syncthreads();
    for (int i = tid; i < ecount; i += 256) {
        int e = e0 + i;
        int s = ei[e];
        int d = ei[E + e];
        unsigned int wb = __float_as_uint(ew[e]);
        int b = d >> 7;
        int off = atomicAdd(&cur[b], 1);
        int pos = lbase[b] + off;
        sstage[pos] = ((unsigned long long)(d & 127) << 49)
                    | ((unsigned long long)(unsigned int)s << 32) | wb;
        smeta[pos] = gbase[b] + off;
    }
    __syncthreads();
    for (int i = tid; i < ecount; i += 256)
        stage[smeta[i]] = sstage[i];
}

// ---------------- binB: per-bucket counting sort -> final CSR epack + rdeg(int2) ----------------
__global__ __launch_bounds__(256) void binB_k(const unsigned long long* __restrict__ stage,
                                              const int* __restrict__ gstart,
                                              unsigned long long* __restrict__ epack,
                                              int2* __restrict__ rdeg, int N) {
    __shared__ unsigned long long lout[2048];
    __shared__ int cnt[128], exc[128], cur[128];
    int b = blockIdx.x;
    int tid = threadIdx.x;
    int base = gstart[b];
    int nb = gstart[b + 1] - base;
    if (tid < 128) { cnt[tid] = 0; cur[tid] = 0; }
    __syncthreads();
    for (int i = tid; i < nb; i += 256)
        atomicAdd(&cnt[(int)((stage[base + i] >> 49) & 127)], 1);
    __syncthreads();
    if (tid < 128) exc[tid] = cnt[tid];
    __syncthreads();
    for (int off = 1; off < 128; off <<= 1) {
        int add = (tid >= off && tid < 128) ? exc[tid - off] : 0;
        __syncthreads();
        if (tid < 128) exc[tid] += add;
        __syncthreads();
    }
    int node0 = b * 128;
    if (tid < 128) {
        exc[tid] -= cnt[tid];  // exclusive
        int node = node0 + tid;
        if (node < N) rdeg[node] = make_int2(base + exc[tid], cnt[tid]);
    }
    __syncthreads();
    for (int i = tid; i < nb; i += 256) {
        unsigned long long v = stage[base + i];
        int dl = (int)((v >> 49) & 127);
        unsigned int src = (unsigned int)((v >> 32) & 0x1FFFF);
        unsigned int wb = (unsigned int)v;
        int pos = exc[dl] + atomicAdd(&cur[dl], 1);
        unsigned long long outv = ((unsigned long long)wb << 32) | src;
        if (pos < 2048) lout[pos] = outv;
        else epack[base + pos] = outv;
    }
    __syncthreads();
    int lim = min(nb, 2048);
    for (int i = tid; i < lim; i += 256)
        epack[base + i] = lout[i];
}

// ---------------- agg1 (lane-private dims, no reduce) ----------------
// 16 nodes per wave; 4 lanes per node; lane owns dims [dimg*16, +16) in 8 f32x2
// accumulators (v_pk_fma_f32). All 4 lanes of a node walk its edges together:
// no cross-lane reduce, no per-node shuffle cost. 16 edge streams in flight.
__global__ __launch_bounds__(256) void agg1_k(const unsigned short* __restrict__ hb,
                                              const int2* __restrict__ rdeg,
                                              const unsigned long long* __restrict__ epack,
                                              unsigned short* __restrict__ outb, int N) {
    int wid = (blockIdx.x * 256 + threadIdx.x) >> 6;
    int lane = threadIdx.x & 63;
    int ng = lane >> 2;     // node-in-wave 0..15
    int dimg = lane & 3;    // dims [dimg*16, dimg*16+16)
    int node = wid * 16 + ng;
    if (node >= N) return;
    int2 rd = rdeg[node];
    int start = rd.x, cnt = rd.y;
    f32x2 acc[8];
#pragma unroll
    for (int q = 0; q < 8; ++q) acc[q] = (f32x2){0.f, 0.f};
    const uint4* hbase = reinterpret_cast<const uint4*>(hb);
    for (int j = 0; j < cnt; ++j) {
        unsigned long long p = epack[start + j];
        float w = __uint_as_float((unsigned int)(p >> 32));
        f32x2 w2 = {w, w};
        unsigned int src = (unsigned int)p;
        const uint4* rp = hbase + (size_t)src * (H_DIM / 8) + dimg * 2;
        uint4 v0 = rp[0];
        uint4 v1 = rp[1];
        acc[0] = fma2(w2, up2(v0.x), acc[0]);
        acc[1] = fma2(w2, up2(v0.y), acc[1]);
        acc[2] = fma2(w2, up2(v0.z), acc[2]);
        acc[3] = fma2(w2, up2(v0.w), acc[3]);
        acc[4] = fma2(w2, up2(v1.x), acc[4]);
        acc[5] = fma2(w2, up2(v1.y), acc[5]);
        acc[6] = fma2(w2, up2(v1.z), acc[6]);
        acc[7] = fma2(w2, up2(v1.w), acc[7]);
    }
    unsigned int pk[8];
#pragma unroll
    for (int q = 0; q < 8; ++q)
        pk[q] = (unsigned int)f2bf(fmaxf(acc[q].x, 0.f))
              | ((unsigned int)f2bf(fmaxf(acc[q].y, 0.f)) << 16);
    uint4* op = reinterpret_cast<uint4*>(outb + (size_t)node * H_DIM + dimg * 16);
    op[0] = make_uint4(pk[0], pk[1], pk[2], pk[3]);
    op[1] = make_uint4(pk[4], pk[5], pk[6], pk[7]);
}

// ---------------- aggv: u[n] = sum_j w_j * uz[src_j]  (thread per node, float4) ----------------
__global__ __launch_bounds__(256) void aggv_k(const float4* __restrict__ uz,
                                              const int2* __restrict__ rdeg,
                                              const unsigned long long* __restrict__ epack,
                                              float4* __restrict__ u, int N) {
    int node = blockIdx.x * 256 + threadIdx.x;
    if (node >= N) return;
    int2 rd = rdeg[node];
    int start = rd.x, cnt = rd.y;
    float4 acc = make_float4(0.f, 0.f, 0.f, 0.f);
    int j = 0;
    for (; j + 3 < cnt; j += 4) {
#pragma unroll
        for (int q = 0; q < 4; ++q) {
            unsigned long long p = epack[start + j + q];
            float w = __uint_as_float((unsigned int)(p >> 32));
            float4 v = uz[(unsigned int)p];
            acc.x = fmaf(w, v.x, acc.x);
            acc.y = fmaf(w, v.y, acc.y);
            acc.z = fmaf(w, v.z, acc.z);
            acc.w = fmaf(w, v.w, acc.w);
        }
    }
    for (; j < cnt; ++j) {
        unsigned long long p = epack[start + j];
        float w = __uint_as_float((unsigned int)(p >> 32));
        float4 v = uz[(unsigned int)p];
        acc.x = fmaf(w, v.x, acc.x);
        acc.y = fmaf(w, v.y, acc.y);
        acc.z = fmaf(w, v.z, acc.z);
        acc.w = fmaf(w, v.w, acc.w);
    }
    u[node] = acc;
}

// ---------------- pair decode ----------------
__global__ __launch_bounds__(256) void pair_k(const float4* __restrict__ u,
                                              const int* __restrict__ pos,  // [2,P] flat
                                              float2* __restrict__ out, int P) {
    int p = blockIdx.x * 256 + threadIdx.x;
    if (p >= P) return;
    int s = pos[p];
    int t = pos[P + p];
    float4 us = u[s];
    float4 ut = u[t];
    union { float f[2]; unsigned long long v; } o;
    o.f[0] = us.x + ut.z;
    o.f[1] = us.y + ut.w;
    __builtin_nontemporal_store(o.v, reinterpret_cast<unsigned long long*>(&out[p]));
}

extern "C" void kernel_launch(void* const* d_in, const int* in_sizes, int n_in,
                              void* d_out, int out_size, void* d_ws, size_t ws_size,
                              hipStream_t stream) {
    const float* x    = (const float*)d_in[0];
    const int*   ei   = (const int*)d_in[1];    // [2,E]
    const float* ew   = (const float*)d_in[2];  // [E]
    const int*   pos  = (const int*)d_in[3];    // [2,P]
    const float* W1   = (const float*)d_in[4];  // [128,64]
    const float* W2   = (const float*)d_in[5];  // [64,64]
    const float* Wlin = (const float*)d_in[6];  // [2,128]
    float* out = (float*)d_out;

    const int N = in_sizes[0] / F_IN;      // 100000
    const int E = in_sizes[2];             // 1000000
    const int P = in_sizes[3] / 2;         // 500000
    const int nbuck = (N + 127) / 128;     // 782

    // workspace layout (bytes)
    char* ws = (char*)d_ws;
    const size_t rowBF = (size_t)N * H_DIM * sizeof(unsigned short);  // 12.8 MB
    unsigned short* hb   = (unsigned short*)ws;                // gemm1 out (bf16)
    unsigned short* a1b  = (unsigned short*)(ws + rowBF);      // relu(agg1) (bf16)
    float4*         uz   = (float4*)(ws + 2 * rowBF);          // N float4
    float4*         u    = uz + N;                             // N float4
    unsigned long long* epack = (unsigned long long*)((char*)(u + N));
    unsigned long long* stage = epack + E;
    int* ghist   = (int*)(stage + E);
    int* gstart  = ghist + NBUCK_MAX;          // nbuck+1
    int* gcursor = gstart + NBUCK_MAX + 1;
    int2* rdeg   = (int2*)(gcursor + NBUCK_MAX);
    size_t wf_off = (((size_t)((char*)(rdeg + N) - ws)) + 15) & ~(size_t)15;
    unsigned short* wf1 = (unsigned short*)(ws + wf_off);      // 16 KB
    unsigned short* wf2 = wf1 + 4 * 4 * 64 * 8;                // 8 KB

    // weight prepack (single launch: 4 blocks W1 + 2 blocks W2)
    prepack_k<<<6, 256, 0, stream>>>(W1, W2, wf1, wf2);

    // conv1 matmul (x f32 -> bf16 in-register) -> hb
    gemm1_k<<<(N + 63) / 64, 256, 0, stream>>>(x, wf1, hb, N);

    // binning sort -> CSR (epack, rdeg)
    hipMemsetAsync(ghist, 0, (size_t)nbuck * sizeof(int), stream);
    ghist_k<<<(E + 8191) / 8192, 256, 0, stream>>>(ei, ghist, E, nbuck);
    gscan_k<<<1, 256, 0, stream>>>(ghist, gstart, gcursor, nbuck, E);
    binA_k<<<(E + 4095) / 4096, 256, 0, stream>>>(ei, ew, gcursor, stage, E, nbuck);
    binB_k<<<nbuck, 256, 0, stream>>>(stage, gstart, epack, rdeg, N);

    // agg1: hb -> a1b (bf16, relu fused); 64 nodes per 256-thread block
    agg1_k<<<(N + 63) / 64, 256, 0, stream>>>(hb, rdeg, epack, a1b, N);
    // conv2 matmul + fused projection: a1b -> uz
    gemm2v_k<<<(N + 63) / 64, 256, 0, stream>>>(a1b, wf2, Wlin, uz, N);
    // agg2 on projected vectors: uz -> u
    aggv_k<<<(N + 255) / 256, 256, 0, stream>>>(uz, rdeg, epack, u, N);
    // pair decode
    pair_k<<<(P + 255) / 256, 256, 0, stream>>>(u, pos, (float2*)out, P);
}